// Round 6
// baseline (206.990 us; speedup 1.0000x reference)
//
#include <hip/hip_runtime.h>

typedef unsigned short u16;
typedef __bf16 bf16x8 __attribute__((ext_vector_type(8)));
typedef __bf16 bf16x4 __attribute__((ext_vector_type(4)));
typedef float f32x4 __attribute__((ext_vector_type(4)));

#define SC2 0.18033688f  // (1/sqrt(64)) * log2(e); folded into Q in gemm_qkv epilogue

__device__ __forceinline__ u16 f2bf(float f) {
    union { float f; unsigned int i; } v;
    v.f = f;
    unsigned int u = v.i;
    return (u16)((u + 0x7fffu + ((u >> 16) & 1u)) >> 16);  // RNE
}

// async global->LDS DMA, 16B/lane; LDS dest = wave-uniform base + lane*16
__device__ __forceinline__ void dma16(const void* g, void* l) {
    __builtin_amdgcn_global_load_lds(
        (__attribute__((address_space(1))) void*)g,
        (__attribute__((address_space(3))) void*)l, 16, 0, 0);
}

// Swizzle scheme: buffers staged into [row][64] LDS tiles store (row, col) at
// col ^ (key<<3). Q-half of QKg / Vgt / ATT / xbf / WT use key = row&7.
// K-half of QKg uses key = (row>>2)&7 so that after sigma-staging the LDS
// compensation key becomes l16&7 (conflict-free frag reads, same as Q).
// LDS GEOMETRY RULE (measured r5): 16-lane row-parallel ds_read_b128 tiles
// must keep 128B row stride. [64][128] (256B stride) measured a 4-way
// conflict on every V read (4.19M cycles/dispatch, +5us); [64][64] is clean.

// ---- fused transpose+cvt+swizzle: 4x W[k][n] f32 -> WT[n][k^((n&7)<<3)] bf16 ----
__global__ __launch_bounds__(256) void cvt_w4(
    const float* __restrict__ W0, const float* __restrict__ W1,
    const float* __restrict__ W2, const float* __restrict__ W3,
    u16* __restrict__ out) {
    __shared__ u16 t[32][33];
    int z = blockIdx.z;
    const float* in = (z == 0) ? W0 : (z == 1) ? W1 : (z == 2) ? W2 : W3;
    u16* o = out + (size_t)z * 1048576;
    int bx = blockIdx.x * 32, by = blockIdx.y * 32;
    int tx = threadIdx.x & 31, ty = threadIdx.x >> 5;
#pragma unroll
    for (int i = 0; i < 32; i += 8)
        t[ty + i][tx] = f2bf(in[(size_t)(by + ty + i) * 1024 + bx + tx]);
    __syncthreads();
#pragma unroll
    for (int i = 0; i < 32; i += 8) {
        int n = bx + ty + i, k = by + tx;
        o[(size_t)n * 1024 + (k ^ ((n & 7) << 3))] = t[tx][ty + i];
    }
}

// ---- f32 -> bf16 + swizzle: x[s][k] -> xbf[s][k^((s&7)<<3)] ----
__global__ __launch_bounds__(256) void cvt_x(const float* __restrict__ in,
                                             u16* __restrict__ out) {
    int i = blockIdx.x * 256 + threadIdx.x;
    int s = i >> 8, k = (i & 255) * 4;
    float4 f = reinterpret_cast<const float4*>(in)[i];
    ushort4 h;
    h.x = f2bf(f.x); h.y = f2bf(f.y); h.z = f2bf(f.z); h.w = f2bf(f.w);
    *reinterpret_cast<ushort4*>(&out[(size_t)s * 1024 + (k ^ ((s & 7) << 3))]) = h;
}

// ---- QKV GEMM: seg 0/1 -> QKg[b][s][2048] (q|k), seg 2 -> Vgt[b*1024+v][s] ----
// Q cols keyed (s&7); K cols keyed ((s>>2)&7); Vgt keyed (v&7).
// Q values pre-scaled by SC2 so attention's softmax is a bare exp2. (Q-tile in
// QKg is later overwritten by attention's output, so no other reader sees the
// scaled values.)
__global__ __launch_bounds__(256) void gemm_qkv(
    const u16* __restrict__ xbf, const u16* __restrict__ wt,
    const float* __restrict__ bq, const float* __restrict__ bk,
    const float* __restrict__ bv,
    u16* __restrict__ qkg, u16* __restrict__ vgt) {
    __shared__ __align__(16) u16 As[128 * 64];
    __shared__ __align__(16) u16 Bs[128 * 64];

    int tid = threadIdx.x;
    int m0 = blockIdx.y * 128, n0 = blockIdx.x * 128;
    int wave = tid >> 6, lane = tid & 63;
    int wm = (wave >> 1) * 64, wn = (wave & 1) * 64;
    int l16 = lane & 15, quad = lane >> 4;
    int sl = l16 & 7;

    int seg = n0 >> 10;
    int n0r = n0 & 1023;
    const u16* WT = wt + (size_t)seg * 1048576;
    bool swp = (seg == 2);

    f32x4 acc[4][4];
#pragma unroll
    for (int mi = 0; mi < 4; mi++)
#pragma unroll
        for (int ni = 0; ni < 4; ni++) acc[mi][ni] = (f32x4){0.f, 0.f, 0.f, 0.f};

    int rsub = lane >> 3, c16 = (lane & 7) * 8;
    for (int k0 = 0; k0 < 1024; k0 += 64) {
#pragma unroll
        for (int i = 0; i < 4; i++) {
            int row = wave * 32 + i * 8 + rsub;
            dma16(&xbf[(size_t)(m0 + row) * 1024 + k0 + c16], &As[wave * 2048 + i * 512]);
            dma16(&WT[(size_t)(n0r + row) * 1024 + k0 + c16], &Bs[wave * 2048 + i * 512]);
        }
        __syncthreads();
        const u16* Am = swp ? Bs : As;
        const u16* Bn = swp ? As : Bs;
#pragma unroll
        for (int kk = 0; kk < 64; kk += 32) {
            int co = ((((kk >> 3) + quad) ^ sl) << 3);
            bf16x8 af[4], bf[4];
#pragma unroll
            for (int mi = 0; mi < 4; mi++)
                af[mi] = *reinterpret_cast<const bf16x8*>(
                    &Am[(wm + mi * 16 + l16) * 64 + co]);
#pragma unroll
            for (int ni = 0; ni < 4; ni++)
                bf[ni] = *reinterpret_cast<const bf16x8*>(
                    &Bn[(wn + ni * 16 + l16) * 64 + co]);
#pragma unroll
            for (int mi = 0; mi < 4; mi++)
#pragma unroll
                for (int ni = 0; ni < 4; ni++)
                    acc[mi][ni] = __builtin_amdgcn_mfma_f32_16x16x32_bf16(
                        af[mi], bf[ni], acc[mi][ni], 0, 0, 0);
        }
        __syncthreads();
    }

    if (!swp) {
        float sc = (seg == 0) ? SC2 : 1.0f;  // fold softmax scale into Q only
#pragma unroll
        for (int ni = 0; ni < 4; ni++) {
            int n = n0 + wn + ni * 16 + l16;  // 0..2047
            float bb = (n < 1024) ? bq[n] : bk[n - 1024];
#pragma unroll
            for (int mi = 0; mi < 4; mi++)
#pragma unroll
                for (int r = 0; r < 4; r++) {
                    int s = m0 + wm + mi * 16 + quad * 4 + r;
                    int key = (seg == 0) ? (s & 7) : ((s >> 2) & 7);
                    int col = n ^ (key << 3);
                    qkg[(size_t)(s >> 11) * 4194304 + (size_t)(s & 2047) * 2048 + col] =
                        f2bf((acc[mi][ni][r] + bb) * sc);
                }
        }
    } else {
#pragma unroll
        for (int mi = 0; mi < 4; mi++)
#pragma unroll
            for (int r = 0; r < 4; r++) {
                int v = n0r + wm + mi * 16 + quad * 4 + r;  // 0..1023
                float bb = bv[v];
#pragma unroll
                for (int ni = 0; ni < 4; ni++) {
                    int s = m0 + wn + ni * 16 + l16;
                    int scol = (s & 2047) ^ ((v & 7) << 3);
                    vgt[(size_t)((s >> 11) * 1024 + v) * 2048 + scol] =
                        f2bf(acc[mi][ni][r] + bb);
                }
            }
    }
}

// ---- flash attention, 128-row q-tiles, 8 waves, fixed-C softmax ----
// v7 = v6 with the V bank-conflict fix: Vt split into per-subtile [64][64]
// tiles (128B row stride, the v5-verified conflict-free geometry). KVBLK=128
// retained: one staged tile = TWO 64-key subtiles, sequential against the
// same wave-private Ps buffer; 16 barrier pairs per block.
// Sync protocol (verified in v4):
//   barrier A: s_waitcnt vmcnt(4) + s_barrier   [one asm block]
//   barrier B: s_waitcnt lgkmcnt(0) + s_barrier [one asm block]
// Ks subtile row r holds global key t*64 + 4*(r&15)+(r>>4); K storage key
// ((s>>2)&7) makes the staged compensation key l16&7 (conflict-free reads).
// Accumulation order over keys identical to v5/v6 -> bit-identical output.
// Output overwrites this block's own Q-tile in QKg (sole reader = this block).
__global__ __launch_bounds__(512) void attention_kern(
    u16* __restrict__ qkg, const u16* __restrict__ vgt) {
    __shared__ __align__(16) u16 Ks[2][128 * 64];   // two sigma-permuted subtiles
    __shared__ __align__(16) u16 Vt[2][2][64 * 64]; // [buf][t][hd][key64]
    __shared__ __align__(16) u16 Ps[128 * 64];      // [qrow][key-in-subtile]

    int tid = threadIdx.x;
    // XCD swizzle (512 blocks, 8 XCDs, bijective): XCD x gets logical ids
    // [x*64, x*64+64) = all 16 q-tiles of 4 consecutive (h,b) groups.
    int bid = blockIdx.x;
    int id = (bid & 7) * 64 + (bid >> 3);
    int qt = id & 15, h = (id >> 4) & 15, b = id >> 8;

    int wave = tid >> 6, lane = tid & 63;
    int l16 = lane & 15, quad = lane >> 4;
    int rsub = lane >> 3, c16 = (lane & 7) * 8;
    int sl = l16 & 7;

    u16* qb = qkg + (size_t)b * 4194304 + (size_t)(qt * 128) * 2048 + h * 64;
    const u16* kb = qkg + (size_t)b * 4194304 + 1024 + h * 64;
    const u16* vb = vgt + (size_t)(b * 1024 + h * 64) * 2048;

    // Q fragments straight to registers (row wave*16+l16, swizzle key l16&7)
    bf16x8 qf[2];
    {
        const u16* qr = qb + (size_t)(wave * 16 + l16) * 2048;
        qf[0] = *reinterpret_cast<const bf16x8*>(&qr[(quad ^ sl) << 3]);
        qf[1] = *reinterpret_cast<const bf16x8*>(&qr[((4 + quad) ^ sl) << 3]);
    }

    bf16x8 onef;
#pragma unroll
    for (int i = 0; i < 8; i++) onef[i] = (__bf16)1.0f;

    f32x4 o[4], ls;
#pragma unroll
    for (int ni = 0; ni < 4; ni++) o[ni] = (f32x4){0.f, 0.f, 0.f, 0.f};
    ls = (f32x4){0.f, 0.f, 0.f, 0.f};

    // staging maps (per thread, per subtile i):
    //   K: LDS row i*64 + wave*8 + rsub, chunk c16; src key row i*64 + sigma
    //   V: LDS tile [i], row wave*8 + rsub (hd), chunk c16; src physical col
    //      window i*64 + c16 (Vgt swizzle key v&7 = row&7, window-invariant)
    int r8 = wave * 8 + rsub;             // 0..63 (row within subtile)
    int gk = 4 * (r8 & 15) + (r8 >> 4);   // sigma(row) for K

    auto STAGE = [&](int kt, int bi) {
        const u16* ktb = kb + (size_t)(kt * 128) * 2048;
        const u16* vtb = vb + kt * 128;
#pragma unroll
        for (int i = 0; i < 2; i++) {
            dma16(&ktb[(size_t)(i * 64 + gk) * 2048 + c16],
                  &Ks[bi][i * 4096 + wave * 512]);
            dma16(&vtb[(size_t)r8 * 2048 + i * 64 + c16],
                  &Vt[bi][i][wave * 512]);
        }
    };

    STAGE(0, 0);

    for (int kt = 0; kt < 16; kt++) {
        int cur = kt & 1;
        // barrier A: prefetch next tile, wait only for the CURRENT tile's DMAs
        // (4 per thread; the 4 just-issued prefetch DMAs stay in flight)
        if (kt < 15) {
            STAGE(kt + 1, cur ^ 1);
            asm volatile("s_waitcnt vmcnt(4)\n\ts_barrier" ::: "memory");
        } else {
            asm volatile("s_waitcnt vmcnt(0)\n\ts_barrier" ::: "memory");
        }

#pragma unroll
        for (int t = 0; t < 2; t++) {
            // S = Q K^T for subtile t (cols carry sigma labels)
            f32x4 s[4];
#pragma unroll
            for (int ni = 0; ni < 4; ni++) s[ni] = (f32x4){0.f, 0.f, 0.f, 0.f};
#pragma unroll
            for (int kk = 0; kk < 64; kk += 32) {
                int co = ((((kk >> 3) + quad) ^ sl) << 3);
                bf16x8 af = qf[kk >> 5];
#pragma unroll
                for (int ni = 0; ni < 4; ni++) {
                    bf16x8 bfr = *reinterpret_cast<const bf16x8*>(
                        &Ks[cur][(t * 64 + ni * 16 + l16) * 64 + co]);
                    s[ni] = __builtin_amdgcn_mfma_f32_16x16x32_bf16(
                        af, bfr, s[ni], 0, 0, 0);
                }
            }

            // p = exp2(s) (SC2 pre-folded into Q); packed b64 Ps write at
            // natural key positions 4*l16+ni (wave-private rows; per-wave
            // in-order LDS pipe orders the t=1 overwrite after t=0's reads)
#pragma unroll
            for (int r = 0; r < 4; r++) {
                f32x4 pf = {__builtin_amdgcn_exp2f(s[0][r]),
                            __builtin_amdgcn_exp2f(s[1][r]),
                            __builtin_amdgcn_exp2f(s[2][r]),
                            __builtin_amdgcn_exp2f(s[3][r])};
                bf16x4 pb = __builtin_convertvector(pf, bf16x4);
                int q = wave * 16 + quad * 4 + r;
                *reinterpret_cast<bf16x4*>(
                    &Ps[q * 64 + (((l16 >> 1) ^ (q & 7)) << 3) + (l16 & 1) * 4]) = pb;
            }

            // O += P V ; ls += P @ ones (row-sum on the matrix pipe)
#pragma unroll
            for (int kk = 0; kk < 64; kk += 32) {
                int co = ((((kk >> 3) + quad) ^ sl) << 3);
                bf16x8 af = *reinterpret_cast<const bf16x8*>(
                    &Ps[(wave * 16 + l16) * 64 + co]);
                ls = __builtin_amdgcn_mfma_f32_16x16x32_bf16(af, onef, ls, 0, 0, 0);
#pragma unroll
                for (int ni = 0; ni < 4; ni++) {
                    bf16x8 bfr = *reinterpret_cast<const bf16x8*>(
                        &Vt[cur][t][(ni * 16 + l16) * 64 + co]);
                    o[ni] = __builtin_amdgcn_mfma_f32_16x16x32_bf16(
                        af, bfr, o[ni], 0, 0, 0);
                }
            }
        }
        // barrier B: drain this wave's DS reads, then sync -> buf[cur] free
        asm volatile("s_waitcnt lgkmcnt(0)\n\ts_barrier" ::: "memory");
    }

    // ls[r] holds the full row sum (all 16 C-columns identical); no shfl needed
    float inv[4];
#pragma unroll
    for (int r = 0; r < 4; r++) inv[r] = __builtin_amdgcn_rcpf(ls[r]);
    // write ATT over this block's own Q-tile (cols h*64.., rows qt*128..), key s&7
#pragma unroll
    for (int ni = 0; ni < 4; ni++)
#pragma unroll
        for (int r = 0; r < 4; r++) {
            int s = qt * 128 + wave * 16 + quad * 4 + r;  // 0..2047
            int d = h * 64 + ni * 16 + l16;
            qkg[(size_t)b * 4194304 + (size_t)s * 2048 + (d ^ ((s & 7) << 3))] =
                f2bf(o[ni][r] * inv[r]);
        }
}

// ---- out-projection: ATT (QKg q-half, ld 2048) @ WoT -> f32 out, 128x64 tiles ----
__global__ __launch_bounds__(256) void gemm_out(
    const u16* __restrict__ attb, const u16* __restrict__ wot,
    const float* __restrict__ bo, float* __restrict__ out) {
    __shared__ __align__(16) u16 As[128 * 64];
    __shared__ __align__(16) u16 Bs[64 * 64];

    int tid = threadIdx.x;
    int m0 = blockIdx.y * 128, n0 = blockIdx.x * 64;
    int wave = tid >> 6, lane = tid & 63;
    int wm = (wave >> 1) * 64, wn = (wave & 1) * 32;
    int l16 = lane & 15, quad = lane >> 4;
    int sl = l16 & 7;
    int rsub = lane >> 3, c16 = (lane & 7) * 8;

    f32x4 acc[4][2];
#pragma unroll
    for (int mi = 0; mi < 4; mi++)
#pragma unroll
        for (int ni = 0; ni < 2; ni++) acc[mi][ni] = (f32x4){0.f, 0.f, 0.f, 0.f};

    for (int k0 = 0; k0 < 1024; k0 += 64) {
#pragma unroll
        for (int i = 0; i < 4; i++) {
            int row = wave * 32 + i * 8 + rsub;
            dma16(&attb[(size_t)(m0 + row) * 2048 + k0 + c16], &As[wave * 2048 + i * 512]);
        }
#pragma unroll
        for (int i = 0; i < 2; i++) {
            int row = wave * 16 + i * 8 + rsub;
            dma16(&wot[(size_t)(n0 + row) * 1024 + k0 + c16], &Bs[wave * 1024 + i * 512]);
        }
        __syncthreads();
#pragma unroll
        for (int kk = 0; kk < 64; kk += 32) {
            int co = ((((kk >> 3) + quad) ^ sl) << 3);
            bf16x8 af[4], bf[2];
#pragma unroll
            for (int mi = 0; mi < 4; mi++)
                af[mi] = *reinterpret_cast<const bf16x8*>(
                    &As[(wm + mi * 16 + l16) * 64 + co]);
#pragma unroll
            for (int ni = 0; ni < 2; ni++)
                bf[ni] = *reinterpret_cast<const bf16x8*>(
                    &Bs[(wn + ni * 16 + l16) * 64 + co]);
#pragma unroll
            for (int mi = 0; mi < 4; mi++)
#pragma unroll
                for (int ni = 0; ni < 2; ni++)
                    acc[mi][ni] = __builtin_amdgcn_mfma_f32_16x16x32_bf16(
                        af[mi], bf[ni], acc[mi][ni], 0, 0, 0);
        }
        __syncthreads();
    }

#pragma unroll
    for (int ni = 0; ni < 2; ni++) {
        int n = n0 + wn + ni * 16 + l16;
        float bb = bo[n];
#pragma unroll
        for (int mi = 0; mi < 4; mi++)
#pragma unroll
            for (int r = 0; r < 4; r++)
                out[(size_t)(m0 + wm + mi * 16 + quad * 4 + r) * 1024 + n] =
                    acc[mi][ni][r] + bb;
    }
}

// ---------------- launch ----------------
extern "C" void kernel_launch(void* const* d_in, const int* in_sizes, int n_in,
                              void* d_out, int out_size, void* d_ws, size_t ws_size,
                              hipStream_t stream) {
    const float* x  = (const float*)d_in[0];
    const float* Wq = (const float*)d_in[1];
    const float* bq = (const float*)d_in[2];
    const float* Wk = (const float*)d_in[3];
    const float* bk = (const float*)d_in[4];
    const float* Wv = (const float*)d_in[5];
    const float* bv = (const float*)d_in[6];
    const float* Wo = (const float*)d_in[7];
    const float* bo = (const float*)d_in[8];

    // d_out scratch: WqT@0, WkT@2MB, WvT@4MB, WoT@6MB, xbf@8MB (all dead before
    // gemm_out's f32 write). ws: QKg[2][2048][2048]@0 (16MB, q-half becomes ATT),
    // Vgt[2048][2048]@16MB (8MB, becomes WoT park).
    u16* WT  = (u16*)d_out;
    u16* xbf = (u16*)d_out + 4 * 1048576;
    u16* QKg = (u16*)d_ws;
    u16* Vgt = (u16*)d_ws + 8 * 1048576;

    cvt_w4<<<dim3(32, 32, 4), 256, 0, stream>>>(Wq, Wk, Wv, Wo, WT);
    cvt_x<<<4096, 256, 0, stream>>>(x, xbf);

    gemm_qkv<<<dim3(24, 32), 256, 0, stream>>>(xbf, WT, bq, bk, bv, QKg, Vgt);

    attention_kern<<<dim3(512), 512, 0, stream>>>(QKg, Vgt);

    // park WoT in ws (Vgt dead after attention); out-projection -> f32 d_out
    hipMemcpyAsync(Vgt, WT + 3 * 1048576, (size_t)2 * 1048576,
                   hipMemcpyDeviceToDevice, stream);
    gemm_out<<<dim3(16, 32), 256, 0, stream>>>(QKg, Vgt, bo, (float*)d_out);
}

// Round 9
// 195.518 us; speedup vs baseline: 1.0587x; 1.0587x over previous
//
#include <hip/hip_runtime.h>

typedef unsigned short u16;
typedef __bf16 bf16x8 __attribute__((ext_vector_type(8)));
typedef __bf16 bf16x4 __attribute__((ext_vector_type(4)));
typedef float f32x4 __attribute__((ext_vector_type(4)));

#define SC2 0.18033688f  // (1/sqrt(64)) * log2(e); folded into Q in gemm_qkv epilogue

__device__ __forceinline__ u16 f2bf(float f) {
    union { float f; unsigned int i; } v;
    v.f = f;
    unsigned int u = v.i;
    return (u16)((u + 0x7fffu + ((u >> 16) & 1u)) >> 16);  // RNE
}

// async global->LDS DMA, 16B/lane; LDS dest = wave-uniform base + lane*16
__device__ __forceinline__ void dma16(const void* g, void* l) {
    __builtin_amdgcn_global_load_lds(
        (__attribute__((address_space(1))) void*)g,
        (__attribute__((address_space(3))) void*)l, 16, 0, 0);
}

// Swizzle scheme: buffers staged into [row][64] LDS tiles store (row, col) at
// col ^ (key<<3). Q-half of QKg / Vgt / ATT / xbf / WT use key = row&7.
// K-half of QKg uses key = (row>>2)&7 so that after sigma-staging the LDS
// compensation key becomes l16&7 (conflict-free frag reads, same as Q).
// LDS GEOMETRY RULE (measured r5/r6): keep 128B row stride for the 16-lane
// row-parallel ds_read_b128 tiles; KVBLK=128 variants (80KB LDS) measured
// strictly worse than the KVBLK=64 / 2-blocks-per-CU structure.

// ---- fused transpose+cvt+swizzle: 4x W[k][n] f32 -> WT[n][k^((n&7)<<3)] bf16 ----
__global__ __launch_bounds__(256) void cvt_w4(
    const float* __restrict__ W0, const float* __restrict__ W1,
    const float* __restrict__ W2, const float* __restrict__ W3,
    u16* __restrict__ out) {
    __shared__ u16 t[32][33];
    int z = blockIdx.z;
    const float* in = (z == 0) ? W0 : (z == 1) ? W1 : (z == 2) ? W2 : W3;
    u16* o = out + (size_t)z * 1048576;
    int bx = blockIdx.x * 32, by = blockIdx.y * 32;
    int tx = threadIdx.x & 31, ty = threadIdx.x >> 5;
#pragma unroll
    for (int i = 0; i < 32; i += 8)
        t[ty + i][tx] = f2bf(in[(size_t)(by + ty + i) * 1024 + bx + tx]);
    __syncthreads();
#pragma unroll
    for (int i = 0; i < 32; i += 8) {
        int n = bx + ty + i, k = by + tx;
        o[(size_t)n * 1024 + (k ^ ((n & 7) << 3))] = t[tx][ty + i];
    }
}

// ---- f32 -> bf16 + swizzle: x[s][k] -> xbf[s][k^((s&7)<<3)] ----
__global__ __launch_bounds__(256) void cvt_x(const float* __restrict__ in,
                                             u16* __restrict__ out) {
    int i = blockIdx.x * 256 + threadIdx.x;
    int s = i >> 8, k = (i & 255) * 4;
    float4 f = reinterpret_cast<const float4*>(in)[i];
    ushort4 h;
    h.x = f2bf(f.x); h.y = f2bf(f.y); h.z = f2bf(f.z); h.w = f2bf(f.w);
    *reinterpret_cast<ushort4*>(&out[(size_t)s * 1024 + (k ^ ((s & 7) << 3))]) = h;
}

// ---- QKV GEMM: seg 0/1 -> QKg[b][s][2048] (q|k), seg 2 -> Vgt[b*1024+v][s] ----
// Q cols keyed (s&7); K cols keyed ((s>>2)&7); Vgt keyed (v&7).
// Q values pre-scaled by SC2 so attention's softmax is a bare exp2. (Q-tile in
// QKg is later overwritten by attention's output, so no other reader sees the
// scaled values.)
__global__ __launch_bounds__(256) void gemm_qkv(
    const u16* __restrict__ xbf, const u16* __restrict__ wt,
    const float* __restrict__ bq, const float* __restrict__ bk,
    const float* __restrict__ bv,
    u16* __restrict__ qkg, u16* __restrict__ vgt) {
    __shared__ __align__(16) u16 As[128 * 64];
    __shared__ __align__(16) u16 Bs[128 * 64];

    int tid = threadIdx.x;
    int m0 = blockIdx.y * 128, n0 = blockIdx.x * 128;
    int wave = tid >> 6, lane = tid & 63;
    int wm = (wave >> 1) * 64, wn = (wave & 1) * 64;
    int l16 = lane & 15, quad = lane >> 4;
    int sl = l16 & 7;

    int seg = n0 >> 10;
    int n0r = n0 & 1023;
    const u16* WT = wt + (size_t)seg * 1048576;
    bool swp = (seg == 2);

    f32x4 acc[4][4];
#pragma unroll
    for (int mi = 0; mi < 4; mi++)
#pragma unroll
        for (int ni = 0; ni < 4; ni++) acc[mi][ni] = (f32x4){0.f, 0.f, 0.f, 0.f};

    int rsub = lane >> 3, c16 = (lane & 7) * 8;
    for (int k0 = 0; k0 < 1024; k0 += 64) {
#pragma unroll
        for (int i = 0; i < 4; i++) {
            int row = wave * 32 + i * 8 + rsub;
            dma16(&xbf[(size_t)(m0 + row) * 1024 + k0 + c16], &As[wave * 2048 + i * 512]);
            dma16(&WT[(size_t)(n0r + row) * 1024 + k0 + c16], &Bs[wave * 2048 + i * 512]);
        }
        __syncthreads();
        const u16* Am = swp ? Bs : As;
        const u16* Bn = swp ? As : Bs;
#pragma unroll
        for (int kk = 0; kk < 64; kk += 32) {
            int co = ((((kk >> 3) + quad) ^ sl) << 3);
            bf16x8 af[4], bf[4];
#pragma unroll
            for (int mi = 0; mi < 4; mi++)
                af[mi] = *reinterpret_cast<const bf16x8*>(
                    &Am[(wm + mi * 16 + l16) * 64 + co]);
#pragma unroll
            for (int ni = 0; ni < 4; ni++)
                bf[ni] = *reinterpret_cast<const bf16x8*>(
                    &Bn[(wn + ni * 16 + l16) * 64 + co]);
#pragma unroll
            for (int mi = 0; mi < 4; mi++)
#pragma unroll
                for (int ni = 0; ni < 4; ni++)
                    acc[mi][ni] = __builtin_amdgcn_mfma_f32_16x16x32_bf16(
                        af[mi], bf[ni], acc[mi][ni], 0, 0, 0);
        }
        __syncthreads();
    }

    if (!swp) {
        float sc = (seg == 0) ? SC2 : 1.0f;  // fold softmax scale into Q only
#pragma unroll
        for (int ni = 0; ni < 4; ni++) {
            int n = n0 + wn + ni * 16 + l16;  // 0..2047
            float bb = (n < 1024) ? bq[n] : bk[n - 1024];
#pragma unroll
            for (int mi = 0; mi < 4; mi++)
#pragma unroll
                for (int r = 0; r < 4; r++) {
                    int s = m0 + wm + mi * 16 + quad * 4 + r;
                    int key = (seg == 0) ? (s & 7) : ((s >> 2) & 7);
                    int col = n ^ (key << 3);
                    qkg[(size_t)(s >> 11) * 4194304 + (size_t)(s & 2047) * 2048 + col] =
                        f2bf((acc[mi][ni][r] + bb) * sc);
                }
        }
    } else {
#pragma unroll
        for (int mi = 0; mi < 4; mi++)
#pragma unroll
            for (int r = 0; r < 4; r++) {
                int v = n0r + wm + mi * 16 + quad * 4 + r;  // 0..1023
                float bb = bv[v];
#pragma unroll
                for (int ni = 0; ni < 4; ni++) {
                    int s = m0 + wn + ni * 16 + l16;
                    int scol = (s & 2047) ^ ((v & 7) << 3);
                    vgt[(size_t)((s >> 11) * 1024 + v) * 2048 + scol] =
                        f2bf(acc[mi][ni][r] + bb);
                }
            }
    }
}

// ---- flash attention, 128-row q-tiles, 8 waves, fixed-C softmax ----
// v8 = v5 base (KVBLK=64, the 50.2us-verified structure) + TRIPLE buffer with
// ONE fused barrier per iteration:
//     STAGE(kt+1) -> buf[(kt+1)%3]
//     s_waitcnt vmcnt(2) lgkmcnt(0) ; s_barrier    [single asm block]
//     compute on buf[kt%3]
// Soundness: the lgkmcnt(0) executed at barrier(k) drains each wave's
// compute(k-1) ds_reads BEFORE it arrives. STAGE(kt+1) overwrites the buffer
// last read at compute(kt-2); every wave drained those reads at its
// barrier(kt-1) arrival, and the staging wave passed barrier(kt-1) only after
// all waves arrived => WAR distance = 2 barriers, no timing assumptions.
// vmcnt(2): the only outstanding VM ops at the barrier are STAGE(kt+1)'s 2
// DMAs; waiting to 2 forces STAGE(kt)'s DMAs (and, at kt=0, the qf loads)
// complete. Barriers per block: 64 (v5) -> 32. Buffer rotation by pointer
// swap (register moves only; no runtime-indexed arrays).
// Ks LDS row r holds global key 4*(r&15)+(r>>4); K storage key ((s>>2)&7)
// makes the staged compensation key l16&7 (conflict-free frag reads).
// Math/accumulation order identical to v5 -> bit-identical output.
// Output overwrites this block's own Q-tile in QKg (sole reader = this block).
__global__ __launch_bounds__(512) void attention_kern(
    u16* __restrict__ qkg, const u16* __restrict__ vgt) {
    __shared__ __align__(16) u16 KsB[3][64 * 64];  // sigma-permuted key rows
    __shared__ __align__(16) u16 VtB[3][64 * 64];  // [hd][key]
    __shared__ __align__(16) u16 Ps[128 * 64];     // [qrow][key]

    int tid = threadIdx.x;
    // XCD swizzle (512 blocks, 8 XCDs, bijective): XCD x gets logical ids
    // [x*64, x*64+64) = all 16 q-tiles of 4 consecutive (h,b) groups.
    int bid = blockIdx.x;
    int id = (bid & 7) * 64 + (bid >> 3);
    int qt = id & 15, h = (id >> 4) & 15, b = id >> 8;

    int wave = tid >> 6, lane = tid & 63;
    int l16 = lane & 15, quad = lane >> 4;
    int rsub = lane >> 3, c16 = (lane & 7) * 8;
    int sl = l16 & 7;

    u16* qb = qkg + (size_t)b * 4194304 + (size_t)(qt * 128) * 2048 + h * 64;
    const u16* kb = qkg + (size_t)b * 4194304 + 1024 + h * 64;
    const u16* vb = vgt + (size_t)(b * 1024 + h * 64) * 2048;

    // Q fragments straight to registers (row wave*16+l16, swizzle key l16&7)
    bf16x8 qf[2];
    {
        const u16* qr = qb + (size_t)(wave * 16 + l16) * 2048;
        qf[0] = *reinterpret_cast<const bf16x8*>(&qr[(quad ^ sl) << 3]);
        qf[1] = *reinterpret_cast<const bf16x8*>(&qr[((4 + quad) ^ sl) << 3]);
    }

    bf16x8 onef;
#pragma unroll
    for (int i = 0; i < 8; i++) onef[i] = (__bf16)1.0f;

    f32x4 o[4], ls;
#pragma unroll
    for (int ni = 0; ni < 4; ni++) o[ni] = (f32x4){0.f, 0.f, 0.f, 0.f};
    ls = (f32x4){0.f, 0.f, 0.f, 0.f};

    // staging map (per thread): 1 K chunk + 1 V chunk (16B each) per tile
    int r8 = wave * 8 + rsub;             // 0..63 (LDS row)
    int gk = 4 * (r8 & 15) + (r8 >> 4);   // sigma(row) for K

    auto STAGE = [&](int kt, u16* kd, u16* vd) {
        const u16* ktb = kb + (size_t)(kt * 64) * 2048;
        const u16* vtb = vb + kt * 64;
        dma16(&ktb[(size_t)gk * 2048 + c16], kd + wave * 512);
        dma16(&vtb[(size_t)r8 * 2048 + c16], vd + wave * 512);
    };

    // rotating buffer pointers: k0/v0 = tile kt, k1/v1 = staging target kt+1,
    // k2/v2 = free (staged at kt+2)
    u16 *k0 = KsB[0], *k1 = KsB[1], *k2 = KsB[2];
    u16 *v0 = VtB[0], *v1 = VtB[1], *v2 = VtB[2];

    STAGE(0, k0, v0);

    for (int kt = 0; kt < 32; kt++) {
        // single fused barrier per iteration (see header comment)
        if (kt < 31) {
            STAGE(kt + 1, k1, v1);
            asm volatile("s_waitcnt vmcnt(2) lgkmcnt(0)\n\ts_barrier" ::: "memory");
        } else {
            asm volatile("s_waitcnt vmcnt(0) lgkmcnt(0)\n\ts_barrier" ::: "memory");
        }

        // S = Q K^T (cols carry sigma labels; all frag reads use key l16&7)
        f32x4 s[4];
#pragma unroll
        for (int ni = 0; ni < 4; ni++) s[ni] = (f32x4){0.f, 0.f, 0.f, 0.f};
#pragma unroll
        for (int kk = 0; kk < 64; kk += 32) {
            int co = ((((kk >> 3) + quad) ^ sl) << 3);
            bf16x8 af = qf[kk >> 5];
#pragma unroll
            for (int ni = 0; ni < 4; ni++) {
                bf16x8 bfr = *reinterpret_cast<const bf16x8*>(
                    &k0[(ni * 16 + l16) * 64 + co]);
                s[ni] = __builtin_amdgcn_mfma_f32_16x16x32_bf16(af, bfr, s[ni], 0, 0, 0);
            }
        }

        // p = exp2(s) (SC2 pre-folded into Q); packed b64 Ps write at natural
        // key positions 4*l16+ni (wave-private rows; per-wave in-order LDS
        // pipe orders this write before the PV reads below)
#pragma unroll
        for (int r = 0; r < 4; r++) {
            f32x4 pf = {__builtin_amdgcn_exp2f(s[0][r]),
                        __builtin_amdgcn_exp2f(s[1][r]),
                        __builtin_amdgcn_exp2f(s[2][r]),
                        __builtin_amdgcn_exp2f(s[3][r])};
            bf16x4 pb = __builtin_convertvector(pf, bf16x4);
            int q = wave * 16 + quad * 4 + r;
            *reinterpret_cast<bf16x4*>(
                &Ps[q * 64 + (((l16 >> 1) ^ (q & 7)) << 3) + (l16 & 1) * 4]) = pb;
        }

        // O += P V ; ls += P @ ones (row-sum on the matrix pipe; with constant
        // B the fragment layout is irrelevant: D[i][j] = sum_k P[i][k])
#pragma unroll
        for (int kk = 0; kk < 64; kk += 32) {
            int co = ((((kk >> 3) + quad) ^ sl) << 3);
            bf16x8 af = *reinterpret_cast<const bf16x8*>(
                &Ps[(wave * 16 + l16) * 64 + co]);
            ls = __builtin_amdgcn_mfma_f32_16x16x32_bf16(af, onef, ls, 0, 0, 0);
#pragma unroll
            for (int ni = 0; ni < 4; ni++) {
                bf16x8 bfr = *reinterpret_cast<const bf16x8*>(
                    &v0[(ni * 16 + l16) * 64 + co]);
                o[ni] = __builtin_amdgcn_mfma_f32_16x16x32_bf16(af, bfr, o[ni], 0, 0, 0);
            }
        }

        // rotate buffers (register moves only)
        u16* tk = k0; k0 = k1; k1 = k2; k2 = tk;
        u16* tv = v0; v0 = v1; v1 = v2; v2 = tv;
    }

    // ls[r] holds the full row sum (all 16 C-columns identical); no shfl needed
    float inv[4];
#pragma unroll
    for (int r = 0; r < 4; r++) inv[r] = __builtin_amdgcn_rcpf(ls[r]);
    // write ATT over this block's own Q-tile (cols h*64.., rows qt*128..), key s&7
#pragma unroll
    for (int ni = 0; ni < 4; ni++)
#pragma unroll
        for (int r = 0; r < 4; r++) {
            int s = qt * 128 + wave * 16 + quad * 4 + r;  // 0..2047
            int d = h * 64 + ni * 16 + l16;
            qkg[(size_t)b * 4194304 + (size_t)s * 2048 + (d ^ ((s & 7) << 3))] =
                f2bf(o[ni][r] * inv[r]);
        }
}

// ---- out-projection: ATT (QKg q-half, ld 2048) @ WoT -> f32 out, 128x64 tiles ----
__global__ __launch_bounds__(256) void gemm_out(
    const u16* __restrict__ attb, const u16* __restrict__ wot,
    const float* __restrict__ bo, float* __restrict__ out) {
    __shared__ __align__(16) u16 As[128 * 64];
    __shared__ __align__(16) u16 Bs[64 * 64];

    int tid = threadIdx.x;
    int m0 = blockIdx.y * 128, n0 = blockIdx.x * 64;
    int wave = tid >> 6, lane = tid & 63;
    int wm = (wave >> 1) * 64, wn = (wave & 1) * 32;
    int l16 = lane & 15, quad = lane >> 4;
    int sl = l16 & 7;
    int rsub = lane >> 3, c16 = (lane & 7) * 8;

    f32x4 acc[4][2];
#pragma unroll
    for (int mi = 0; mi < 4; mi++)
#pragma unroll
        for (int ni = 0; ni < 2; ni++) acc[mi][ni] = (f32x4){0.f, 0.f, 0.f, 0.f};

    for (int k0 = 0; k0 < 1024; k0 += 64) {
#pragma unroll
        for (int i = 0; i < 4; i++) {
            int row = wave * 32 + i * 8 + rsub;
            dma16(&attb[(size_t)(m0 + row) * 2048 + k0 + c16], &As[wave * 2048 + i * 512]);
        }
#pragma unroll
        for (int i = 0; i < 2; i++) {
            int row = wave * 16 + i * 8 + rsub;
            dma16(&wot[(size_t)(n0 + row) * 1024 + k0 + c16], &Bs[wave * 1024 + i * 512]);
        }
        __syncthreads();
#pragma unroll
        for (int kk = 0; kk < 64; kk += 32) {
            int co = ((((kk >> 3) + quad) ^ sl) << 3);
            bf16x8 af[4], bf[2];
#pragma unroll
            for (int mi = 0; mi < 4; mi++)
                af[mi] = *reinterpret_cast<const bf16x8*>(
                    &As[(wm + mi * 16 + l16) * 64 + co]);
#pragma unroll
            for (int ni = 0; ni < 2; ni++)
                bf[ni] = *reinterpret_cast<const bf16x8*>(
                    &Bs[(wn + ni * 16 + l16) * 64 + co]);
#pragma unroll
            for (int mi = 0; mi < 4; mi++)
#pragma unroll
                for (int ni = 0; ni < 2; ni++)
                    acc[mi][ni] = __builtin_amdgcn_mfma_f32_16x16x32_bf16(
                        af[mi], bf[ni], acc[mi][ni], 0, 0, 0);
        }
        __syncthreads();
    }

#pragma unroll
    for (int ni = 0; ni < 2; ni++) {
        int n = n0 + wn + ni * 16 + l16;
        float bb = bo[n];
#pragma unroll
        for (int mi = 0; mi < 4; mi++)
#pragma unroll
            for (int r = 0; r < 4; r++)
                out[(size_t)(m0 + wm + mi * 16 + quad * 4 + r) * 1024 + n] =
                    acc[mi][ni][r] + bb;
    }
}

// ---------------- launch ----------------
extern "C" void kernel_launch(void* const* d_in, const int* in_sizes, int n_in,
                              void* d_out, int out_size, void* d_ws, size_t ws_size,
                              hipStream_t stream) {
    const float* x  = (const float*)d_in[0];
    const float* Wq = (const float*)d_in[1];
    const float* bq = (const float*)d_in[2];
    const float* Wk = (const float*)d_in[3];
    const float* bk = (const float*)d_in[4];
    const float* Wv = (const float*)d_in[5];
    const float* bv = (const float*)d_in[6];
    const float* Wo = (const float*)d_in[7];
    const float* bo = (const float*)d_in[8];

    // d_out scratch: WqT@0, WkT@2MB, WvT@4MB, WoT@6MB, xbf@8MB (all dead before
    // gemm_out's f32 write). ws: QKg[2][2048][2048]@0 (16MB, q-half becomes ATT),
    // Vgt[2048][2048]@16MB (8MB, becomes WoT park).
    u16* WT  = (u16*)d_out;
    u16* xbf = (u16*)d_out + 4 * 1048576;
    u16* QKg = (u16*)d_ws;
    u16* Vgt = (u16*)d_ws + 8 * 1048576;

    cvt_w4<<<dim3(32, 32, 4), 256, 0, stream>>>(Wq, Wk, Wv, Wo, WT);
    cvt_x<<<4096, 256, 0, stream>>>(x, xbf);

    gemm_qkv<<<dim3(24, 32), 256, 0, stream>>>(xbf, WT, bq, bk, bv, QKg, Vgt);

    attention_kern<<<dim3(512), 512, 0, stream>>>(QKg, Vgt);

    // park WoT in ws (Vgt dead after attention); out-projection -> f32 d_out
    hipMemcpyAsync(Vgt, WT + 3 * 1048576, (size_t)2 * 1048576,
                   hipMemcpyDeviceToDevice, stream);
    gemm_out<<<dim3(16, 32), 256, 0, stream>>>(QKg, Vgt, bo, (float*)d_out);
}

// Round 10
// 193.506 us; speedup vs baseline: 1.0697x; 1.0104x over previous
//
#include <hip/hip_runtime.h>

typedef unsigned short u16;
typedef __bf16 bf16x8 __attribute__((ext_vector_type(8)));
typedef __bf16 bf16x4 __attribute__((ext_vector_type(4)));
typedef float f32x4 __attribute__((ext_vector_type(4)));

#define SC2 0.18033688f  // (1/sqrt(64)) * log2(e); folded into Q in gemm_qkv epilogue

__device__ __forceinline__ u16 f2bf(float f) {
    union { float f; unsigned int i; } v;
    v.f = f;
    unsigned int u = v.i;
    return (u16)((u + 0x7fffu + ((u >> 16) & 1u)) >> 16);  // RNE
}

// async global->LDS DMA, 16B/lane; LDS dest = wave-uniform base + lane*16
__device__ __forceinline__ void dma16(const void* g, void* l) {
    __builtin_amdgcn_global_load_lds(
        (__attribute__((address_space(1))) void*)g,
        (__attribute__((address_space(3))) void*)l, 16, 0, 0);
}

// Swizzle scheme: buffers staged into [row][64] LDS tiles store (row, col) at
// col ^ (key<<3). Q-half of QKg / Vgt / ATT / xbf / WT use key = row&7.
// K-half of QKg uses key = (row>>2)&7 so that after sigma-staging the LDS
// compensation key becomes l16&7 (conflict-free frag reads, same as Q).
// LDS GEOMETRY RULE (measured r5/r6): keep 128B row stride for the 16-lane
// row-parallel ds_read_b128 tiles; KVBLK=128 variants (80KB LDS) measured
// strictly worse than the KVBLK=64 / 2-blocks-per-CU structure.
// SYNC TEMPLATE (verified r9): triple-buffer + ONE fused barrier per iter
// (s_waitcnt vmcnt(N_inflight) lgkmcnt(0); s_barrier in a single asm block).
// WAR distance = 2 barriers. Do NOT use a bare s_barrier (r1/r2 races).

// ---- fused transpose+cvt+swizzle: 4x W[k][n] f32 -> WT[n][k^((n&7)<<3)] bf16 ----
__global__ __launch_bounds__(256) void cvt_w4(
    const float* __restrict__ W0, const float* __restrict__ W1,
    const float* __restrict__ W2, const float* __restrict__ W3,
    u16* __restrict__ out) {
    __shared__ u16 t[32][33];
    int z = blockIdx.z;
    const float* in = (z == 0) ? W0 : (z == 1) ? W1 : (z == 2) ? W2 : W3;
    u16* o = out + (size_t)z * 1048576;
    int bx = blockIdx.x * 32, by = blockIdx.y * 32;
    int tx = threadIdx.x & 31, ty = threadIdx.x >> 5;
#pragma unroll
    for (int i = 0; i < 32; i += 8)
        t[ty + i][tx] = f2bf(in[(size_t)(by + ty + i) * 1024 + bx + tx]);
    __syncthreads();
#pragma unroll
    for (int i = 0; i < 32; i += 8) {
        int n = bx + ty + i, k = by + tx;
        o[(size_t)n * 1024 + (k ^ ((n & 7) << 3))] = t[tx][ty + i];
    }
}

// ---- f32 -> bf16 + swizzle: x[s][k] -> xbf[s][k^((s&7)<<3)] ----
__global__ __launch_bounds__(256) void cvt_x(const float* __restrict__ in,
                                             u16* __restrict__ out) {
    int i = blockIdx.x * 256 + threadIdx.x;
    int s = i >> 8, k = (i & 255) * 4;
    float4 f = reinterpret_cast<const float4*>(in)[i];
    ushort4 h;
    h.x = f2bf(f.x); h.y = f2bf(f.y); h.z = f2bf(f.z); h.w = f2bf(f.w);
    *reinterpret_cast<ushort4*>(&out[(size_t)s * 1024 + (k ^ ((s & 7) << 3))]) = h;
}

// ---- QKV GEMM: seg 0/1 -> QKg[b][s][2048] (q|k), seg 2 -> Vgt[b*1024+v][s] ----
// Q cols keyed (s&7); K cols keyed ((s>>2)&7); Vgt keyed (v&7).
// Q values pre-scaled by SC2 so attention's softmax is a bare exp2. (Q-tile in
// QKg is later overwritten by attention's output, so no other reader sees the
// scaled values.)
// NOTE: triple-buffering this kernel needs 96KB LDS -> 1 block/CU (m132-class
// occupancy cliff), and BK=32 breaks the 64-col swizzle group; left as-is.
__global__ __launch_bounds__(256) void gemm_qkv(
    const u16* __restrict__ xbf, const u16* __restrict__ wt,
    const float* __restrict__ bq, const float* __restrict__ bk,
    const float* __restrict__ bv,
    u16* __restrict__ qkg, u16* __restrict__ vgt) {
    __shared__ __align__(16) u16 As[128 * 64];
    __shared__ __align__(16) u16 Bs[128 * 64];

    int tid = threadIdx.x;
    int m0 = blockIdx.y * 128, n0 = blockIdx.x * 128;
    int wave = tid >> 6, lane = tid & 63;
    int wm = (wave >> 1) * 64, wn = (wave & 1) * 64;
    int l16 = lane & 15, quad = lane >> 4;
    int sl = l16 & 7;

    int seg = n0 >> 10;
    int n0r = n0 & 1023;
    const u16* WT = wt + (size_t)seg * 1048576;
    bool swp = (seg == 2);

    f32x4 acc[4][4];
#pragma unroll
    for (int mi = 0; mi < 4; mi++)
#pragma unroll
        for (int ni = 0; ni < 4; ni++) acc[mi][ni] = (f32x4){0.f, 0.f, 0.f, 0.f};

    int rsub = lane >> 3, c16 = (lane & 7) * 8;
    for (int k0 = 0; k0 < 1024; k0 += 64) {
#pragma unroll
        for (int i = 0; i < 4; i++) {
            int row = wave * 32 + i * 8 + rsub;
            dma16(&xbf[(size_t)(m0 + row) * 1024 + k0 + c16], &As[wave * 2048 + i * 512]);
            dma16(&WT[(size_t)(n0r + row) * 1024 + k0 + c16], &Bs[wave * 2048 + i * 512]);
        }
        __syncthreads();
        const u16* Am = swp ? Bs : As;
        const u16* Bn = swp ? As : Bs;
#pragma unroll
        for (int kk = 0; kk < 64; kk += 32) {
            int co = ((((kk >> 3) + quad) ^ sl) << 3);
            bf16x8 af[4], bf[4];
#pragma unroll
            for (int mi = 0; mi < 4; mi++)
                af[mi] = *reinterpret_cast<const bf16x8*>(
                    &Am[(wm + mi * 16 + l16) * 64 + co]);
#pragma unroll
            for (int ni = 0; ni < 4; ni++)
                bf[ni] = *reinterpret_cast<const bf16x8*>(
                    &Bn[(wn + ni * 16 + l16) * 64 + co]);
#pragma unroll
            for (int mi = 0; mi < 4; mi++)
#pragma unroll
                for (int ni = 0; ni < 4; ni++)
                    acc[mi][ni] = __builtin_amdgcn_mfma_f32_16x16x32_bf16(
                        af[mi], bf[ni], acc[mi][ni], 0, 0, 0);
        }
        __syncthreads();
    }

    if (!swp) {
        float sc = (seg == 0) ? SC2 : 1.0f;  // fold softmax scale into Q only
#pragma unroll
        for (int ni = 0; ni < 4; ni++) {
            int n = n0 + wn + ni * 16 + l16;  // 0..2047
            float bb = (n < 1024) ? bq[n] : bk[n - 1024];
#pragma unroll
            for (int mi = 0; mi < 4; mi++)
#pragma unroll
                for (int r = 0; r < 4; r++) {
                    int s = m0 + wm + mi * 16 + quad * 4 + r;
                    int key = (seg == 0) ? (s & 7) : ((s >> 2) & 7);
                    int col = n ^ (key << 3);
                    qkg[(size_t)(s >> 11) * 4194304 + (size_t)(s & 2047) * 2048 + col] =
                        f2bf((acc[mi][ni][r] + bb) * sc);
                }
        }
    } else {
#pragma unroll
        for (int mi = 0; mi < 4; mi++)
#pragma unroll
            for (int r = 0; r < 4; r++) {
                int v = n0r + wm + mi * 16 + quad * 4 + r;  // 0..1023
                float bb = bv[v];
#pragma unroll
                for (int ni = 0; ni < 4; ni++) {
                    int s = m0 + wn + ni * 16 + l16;
                    int scol = (s & 2047) ^ ((v & 7) << 3);
                    vgt[(size_t)((s >> 11) * 1024 + v) * 2048 + scol] =
                        f2bf(acc[mi][ni][r] + bb);
                }
            }
    }
}

// ---- flash attention, 128-row q-tiles, 8 waves, fixed-C softmax ----
// v8 (VERIFIED r9: 47.5us, bit-identical): KVBLK=64 + triple buffer with ONE
// fused barrier per iteration:
//     STAGE(kt+1) -> buf[(kt+1)%3]
//     s_waitcnt vmcnt(2) lgkmcnt(0) ; s_barrier    [single asm block]
//     compute on buf[kt%3]
// Soundness: the lgkmcnt(0) executed at barrier(k) drains each wave's
// compute(k-1) ds_reads BEFORE it arrives. STAGE(kt+1) overwrites the buffer
// last read at compute(kt-2); every wave drained those reads at its
// barrier(kt-1) arrival => WAR distance = 2 barriers, no timing assumptions.
// Ks LDS row r holds global key 4*(r&15)+(r>>4); K storage key ((s>>2)&7)
// makes the staged compensation key l16&7 (conflict-free frag reads).
// Output overwrites this block's own Q-tile in QKg (sole reader = this block).
__global__ __launch_bounds__(512) void attention_kern(
    u16* __restrict__ qkg, const u16* __restrict__ vgt) {
    __shared__ __align__(16) u16 KsB[3][64 * 64];  // sigma-permuted key rows
    __shared__ __align__(16) u16 VtB[3][64 * 64];  // [hd][key]
    __shared__ __align__(16) u16 Ps[128 * 64];     // [qrow][key]

    int tid = threadIdx.x;
    // XCD swizzle (512 blocks, 8 XCDs, bijective): XCD x gets logical ids
    // [x*64, x*64+64) = all 16 q-tiles of 4 consecutive (h,b) groups.
    int bid = blockIdx.x;
    int id = (bid & 7) * 64 + (bid >> 3);
    int qt = id & 15, h = (id >> 4) & 15, b = id >> 8;

    int wave = tid >> 6, lane = tid & 63;
    int l16 = lane & 15, quad = lane >> 4;
    int rsub = lane >> 3, c16 = (lane & 7) * 8;
    int sl = l16 & 7;

    u16* qb = qkg + (size_t)b * 4194304 + (size_t)(qt * 128) * 2048 + h * 64;
    const u16* kb = qkg + (size_t)b * 4194304 + 1024 + h * 64;
    const u16* vb = vgt + (size_t)(b * 1024 + h * 64) * 2048;

    // Q fragments straight to registers (row wave*16+l16, swizzle key l16&7)
    bf16x8 qf[2];
    {
        const u16* qr = qb + (size_t)(wave * 16 + l16) * 2048;
        qf[0] = *reinterpret_cast<const bf16x8*>(&qr[(quad ^ sl) << 3]);
        qf[1] = *reinterpret_cast<const bf16x8*>(&qr[((4 + quad) ^ sl) << 3]);
    }

    bf16x8 onef;
#pragma unroll
    for (int i = 0; i < 8; i++) onef[i] = (__bf16)1.0f;

    f32x4 o[4], ls;
#pragma unroll
    for (int ni = 0; ni < 4; ni++) o[ni] = (f32x4){0.f, 0.f, 0.f, 0.f};
    ls = (f32x4){0.f, 0.f, 0.f, 0.f};

    // staging map (per thread): 1 K chunk + 1 V chunk (16B each) per tile
    int r8 = wave * 8 + rsub;             // 0..63 (LDS row)
    int gk = 4 * (r8 & 15) + (r8 >> 4);   // sigma(row) for K

    auto STAGE = [&](int kt, u16* kd, u16* vd) {
        const u16* ktb = kb + (size_t)(kt * 64) * 2048;
        const u16* vtb = vb + kt * 64;
        dma16(&ktb[(size_t)gk * 2048 + c16], kd + wave * 512);
        dma16(&vtb[(size_t)r8 * 2048 + c16], vd + wave * 512);
    };

    // rotating buffer pointers: k0/v0 = tile kt, k1/v1 = staging target kt+1,
    // k2/v2 = free (staged at kt+2)
    u16 *k0 = KsB[0], *k1 = KsB[1], *k2 = KsB[2];
    u16 *v0 = VtB[0], *v1 = VtB[1], *v2 = VtB[2];

    STAGE(0, k0, v0);

    for (int kt = 0; kt < 32; kt++) {
        // single fused barrier per iteration (see header comment)
        if (kt < 31) {
            STAGE(kt + 1, k1, v1);
            asm volatile("s_waitcnt vmcnt(2) lgkmcnt(0)\n\ts_barrier" ::: "memory");
        } else {
            asm volatile("s_waitcnt vmcnt(0) lgkmcnt(0)\n\ts_barrier" ::: "memory");
        }

        // S = Q K^T (cols carry sigma labels; all frag reads use key l16&7)
        f32x4 s[4];
#pragma unroll
        for (int ni = 0; ni < 4; ni++) s[ni] = (f32x4){0.f, 0.f, 0.f, 0.f};
#pragma unroll
        for (int kk = 0; kk < 64; kk += 32) {
            int co = ((((kk >> 3) + quad) ^ sl) << 3);
            bf16x8 af = qf[kk >> 5];
#pragma unroll
            for (int ni = 0; ni < 4; ni++) {
                bf16x8 bfr = *reinterpret_cast<const bf16x8*>(
                    &k0[(ni * 16 + l16) * 64 + co]);
                s[ni] = __builtin_amdgcn_mfma_f32_16x16x32_bf16(af, bfr, s[ni], 0, 0, 0);
            }
        }

        // p = exp2(s) (SC2 pre-folded into Q); packed b64 Ps write at natural
        // key positions 4*l16+ni (wave-private rows; per-wave in-order LDS
        // pipe orders this write before the PV reads below)
#pragma unroll
        for (int r = 0; r < 4; r++) {
            f32x4 pf = {__builtin_amdgcn_exp2f(s[0][r]),
                        __builtin_amdgcn_exp2f(s[1][r]),
                        __builtin_amdgcn_exp2f(s[2][r]),
                        __builtin_amdgcn_exp2f(s[3][r])};
            bf16x4 pb = __builtin_convertvector(pf, bf16x4);
            int q = wave * 16 + quad * 4 + r;
            *reinterpret_cast<bf16x4*>(
                &Ps[q * 64 + (((l16 >> 1) ^ (q & 7)) << 3) + (l16 & 1) * 4]) = pb;
        }

        // O += P V ; ls += P @ ones (row-sum on the matrix pipe; with constant
        // B the fragment layout is irrelevant: D[i][j] = sum_k P[i][k])
#pragma unroll
        for (int kk = 0; kk < 64; kk += 32) {
            int co = ((((kk >> 3) + quad) ^ sl) << 3);
            bf16x8 af = *reinterpret_cast<const bf16x8*>(
                &Ps[(wave * 16 + l16) * 64 + co]);
            ls = __builtin_amdgcn_mfma_f32_16x16x32_bf16(af, onef, ls, 0, 0, 0);
#pragma unroll
            for (int ni = 0; ni < 4; ni++) {
                bf16x8 bfr = *reinterpret_cast<const bf16x8*>(
                    &v0[(ni * 16 + l16) * 64 + co]);
                o[ni] = __builtin_amdgcn_mfma_f32_16x16x32_bf16(af, bfr, o[ni], 0, 0, 0);
            }
        }

        // rotate buffers (register moves only)
        u16* tk = k0; k0 = k1; k1 = k2; k2 = tk;
        u16* tv = v0; v0 = v1; v1 = v2; v2 = tv;
    }

    // ls[r] holds the full row sum (all 16 C-columns identical); no shfl needed
    float inv[4];
#pragma unroll
    for (int r = 0; r < 4; r++) inv[r] = __builtin_amdgcn_rcpf(ls[r]);
    // write ATT over this block's own Q-tile (cols h*64.., rows qt*128..), key s&7
#pragma unroll
    for (int ni = 0; ni < 4; ni++)
#pragma unroll
        for (int r = 0; r < 4; r++) {
            int s = qt * 128 + wave * 16 + quad * 4 + r;  // 0..2047
            int d = h * 64 + ni * 16 + l16;
            qkg[(size_t)b * 4194304 + (size_t)s * 2048 + (d ^ ((s & 7) << 3))] =
                f2bf(o[ni][r] * inv[r]);
        }
}

// ---- out-projection: ATT (QKg q-half, ld 2048) @ WoT -> f32 out, 128x64 tiles ----
// v2: triple-buffered staging with the r9-verified single-fused-barrier
// template. Per K-iter: STAGE(k+1) into the rotating third buffer, then
// s_waitcnt vmcnt(6) lgkmcnt(0) + s_barrier in ONE asm block (6 DMAs/thread
// per stage stay in flight across the barrier). WAR distance = 2 barriers,
// same soundness proof as attention v8. LDS 24->72KB; grid (512 = 2/CU) was
// already the occupancy binder, so residency is unchanged. Math and
// accumulation order identical -> bit-identical output.
__global__ __launch_bounds__(256) void gemm_out(
    const u16* __restrict__ attb, const u16* __restrict__ wot,
    const float* __restrict__ bo, float* __restrict__ out) {
    __shared__ __align__(16) u16 A3[3][128 * 64];
    __shared__ __align__(16) u16 B3[3][64 * 64];

    int tid = threadIdx.x;
    int m0 = blockIdx.y * 128, n0 = blockIdx.x * 64;
    int wave = tid >> 6, lane = tid & 63;
    int wm = (wave >> 1) * 64, wn = (wave & 1) * 32;
    int l16 = lane & 15, quad = lane >> 4;
    int sl = l16 & 7;
    int rsub = lane >> 3, c16 = (lane & 7) * 8;

    f32x4 acc[4][2];
#pragma unroll
    for (int mi = 0; mi < 4; mi++)
#pragma unroll
        for (int ni = 0; ni < 2; ni++) acc[mi][ni] = (f32x4){0.f, 0.f, 0.f, 0.f};

    // stage K-window k0 into (ad, bd): 4 A-chunks + 2 B-chunks per thread
    auto STAGE = [&](int k0, u16* ad, u16* bd) {
#pragma unroll
        for (int i = 0; i < 4; i++) {
            int row = wave * 32 + i * 8 + rsub;
            dma16(&attb[(size_t)(m0 + row) * 2048 + k0 + c16], ad + wave * 2048 + i * 512);
        }
#pragma unroll
        for (int i = 0; i < 2; i++) {
            int row = wave * 16 + i * 8 + rsub;
            dma16(&wot[(size_t)(n0 + row) * 1024 + k0 + c16], bd + wave * 1024 + i * 512);
        }
    };

    u16 *a0 = A3[0], *a1 = A3[1], *a2 = A3[2];
    u16 *b0 = B3[0], *b1 = B3[1], *b2 = B3[2];

    STAGE(0, a0, b0);

    for (int k = 0; k < 16; k++) {
        // single fused barrier per iteration (r9-verified template)
        if (k < 15) {
            STAGE((k + 1) * 64, a1, b1);
            asm volatile("s_waitcnt vmcnt(6) lgkmcnt(0)\n\ts_barrier" ::: "memory");
        } else {
            asm volatile("s_waitcnt vmcnt(0) lgkmcnt(0)\n\ts_barrier" ::: "memory");
        }
#pragma unroll
        for (int kk = 0; kk < 64; kk += 32) {
            int co = ((((kk >> 3) + quad) ^ sl) << 3);
            bf16x8 af[4], bf[2];
#pragma unroll
            for (int mi = 0; mi < 4; mi++)
                af[mi] = *reinterpret_cast<const bf16x8*>(
                    &a0[(wm + mi * 16 + l16) * 64 + co]);
#pragma unroll
            for (int ni = 0; ni < 2; ni++)
                bf[ni] = *reinterpret_cast<const bf16x8*>(
                    &b0[(wn + ni * 16 + l16) * 64 + co]);
#pragma unroll
            for (int mi = 0; mi < 4; mi++)
#pragma unroll
                for (int ni = 0; ni < 2; ni++)
                    acc[mi][ni] = __builtin_amdgcn_mfma_f32_16x16x32_bf16(
                        af[mi], bf[ni], acc[mi][ni], 0, 0, 0);
        }
        // rotate buffers (register moves only)
        u16* t;
        t = a0; a0 = a1; a1 = a2; a2 = t;
        t = b0; b0 = b1; b1 = b2; b2 = t;
    }

#pragma unroll
    for (int ni = 0; ni < 2; ni++) {
        int n = n0 + wn + ni * 16 + l16;
        float bb = bo[n];
#pragma unroll
        for (int mi = 0; mi < 4; mi++)
#pragma unroll
            for (int r = 0; r < 4; r++)
                out[(size_t)(m0 + wm + mi * 16 + quad * 4 + r) * 1024 + n] =
                    acc[mi][ni][r] + bb;
    }
}

// ---------------- launch ----------------
extern "C" void kernel_launch(void* const* d_in, const int* in_sizes, int n_in,
                              void* d_out, int out_size, void* d_ws, size_t ws_size,
                              hipStream_t stream) {
    const float* x  = (const float*)d_in[0];
    const float* Wq = (const float*)d_in[1];
    const float* bq = (const float*)d_in[2];
    const float* Wk = (const float*)d_in[3];
    const float* bk = (const float*)d_in[4];
    const float* Wv = (const float*)d_in[5];
    const float* bv = (const float*)d_in[6];
    const float* Wo = (const float*)d_in[7];
    const float* bo = (const float*)d_in[8];

    // d_out scratch: WqT@0, WkT@2MB, WvT@4MB, WoT@6MB, xbf@8MB (all dead before
    // gemm_out's f32 write). ws: QKg[2][2048][2048]@0 (16MB, q-half becomes ATT),
    // Vgt[2048][2048]@16MB (8MB, becomes WoT park).
    u16* WT  = (u16*)d_out;
    u16* xbf = (u16*)d_out + 4 * 1048576;
    u16* QKg = (u16*)d_ws;
    u16* Vgt = (u16*)d_ws + 8 * 1048576;

    cvt_w4<<<dim3(32, 32, 4), 256, 0, stream>>>(Wq, Wk, Wv, Wo, WT);
    cvt_x<<<4096, 256, 0, stream>>>(x, xbf);

    gemm_qkv<<<dim3(24, 32), 256, 0, stream>>>(xbf, WT, bq, bk, bv, QKg, Vgt);

    attention_kern<<<dim3(512), 512, 0, stream>>>(QKg, Vgt);

    // park WoT in ws (Vgt dead after attention); out-projection -> f32 d_out
    hipMemcpyAsync(Vgt, WT + 3 * 1048576, (size_t)2 * 1048576,
                   hipMemcpyDeviceToDevice, stream);
    gemm_out<<<dim3(16, 32), 256, 0, stream>>>(QKg, Vgt, bo, (float*)d_out);
}